// Round 1
// baseline (1014.803 us; speedup 1.0000x reference)
//
#include <hip/hip_runtime.h>

typedef unsigned int uint;
typedef unsigned short ushort;
typedef __bf16 bf16x8 __attribute__((ext_vector_type(8)));
typedef float f32x4 __attribute__((ext_vector_type(4)));

#define B_SZ 32
#define N_SEQ 4096
#define ROWS (B_SZ * N_SEQ)   // 131072
#define LN_EPS 1e-5f
#define EPS_SUM 1e-8f
#define QSCALE 0.0625f        // 256^-0.5

__device__ inline float u2f(uint x){ union{uint u; float f;} c; c.u = x; return c.f; }
__device__ inline ushort f2bf(float f){
  union{float f; uint u;} c; c.f = f; uint u = c.u;
  return (ushort)((u + 0x7fffu + ((u >> 16) & 1u)) >> 16);   // RNE
}
__device__ inline uint pack2(float a, float b){ return (uint)f2bf(a) | ((uint)f2bf(b) << 16); }
__device__ inline void unpk8(uint4 u, float* o){
  o[0]=u2f(u.x<<16); o[1]=u2f(u.x&0xffff0000u);
  o[2]=u2f(u.y<<16); o[3]=u2f(u.y&0xffff0000u);
  o[4]=u2f(u.z<<16); o[5]=u2f(u.z&0xffff0000u);
  o[6]=u2f(u.w<<16); o[7]=u2f(u.w&0xffff0000u);
}
__device__ inline f32x4 mfma16(bf16x8 a, bf16x8 b, f32x4 c){
  return __builtin_amdgcn_mfma_f32_16x16x32_bf16(a, b, c, 0, 0, 0);
}

// ---------------------------------------------------------------- prep
// Casts all weights to bf16, computes wb/wg LN-fold vectors, copies
// prev_slots into working slots, zeroes q rows 8..15 (slot padding).
__global__ __launch_bounds__(256) void prep_kernel(
    const float* Wk, const float* Wv, const float* g_in, const float* b_in,
    const float* W_ih, const float* W_hh, const float* W1, const float* W2, const float* Wq,
    const float* prev_slots,
    ushort* Wg, ushort* Wihb, ushort* Whhb, ushort* W1b, ushort* W2b, ushort* Wqb,
    float* wb, float* wg, float* slots, ushort* qb)
{
  __shared__ float ra[4], rb[4];
  int blk = blockIdx.x, t = threadIdx.x;
  if (blk < 1536){                                   // Wg = [Wk;Wv] * g_in  (512x768)
    int idx = blk*256 + t;
    int o = idx / 768, f = idx - o*768;
    float w = (o < 256) ? Wk[o*768 + f] : Wv[(o-256)*768 + f];
    Wg[idx] = f2bf(w * g_in[f]);
  } else if (blk < 2304){
    int idx = (blk-1536)*256 + t; Wihb[idx] = f2bf(W_ih[idx]);
  } else if (blk < 3072){
    int idx = (blk-2304)*256 + t; Whhb[idx] = f2bf(W_hh[idx]);
  } else if (blk < 3328){
    int idx = (blk-3072)*256 + t; W1b[idx] = f2bf(W1[idx]);
  } else if (blk < 3584){
    int idx = (blk-3328)*256 + t; W2b[idx] = f2bf(W2[idx]);
  } else if (blk < 3840){
    int idx = (blk-3584)*256 + t; Wqb[idx] = f2bf(Wq[idx]);
  } else if (blk < 4352){                            // wb[o]=Σ W·b_in ; wg[o]=Σ W·g_in
    int o = blk - 3840;
    float ab = 0.f, ag = 0.f;
    for (int i = 0; i < 3; ++i){
      int f = t + 256*i;
      float w = (o < 256) ? Wk[o*768 + f] : Wv[(o-256)*768 + f];
      ab += w * b_in[f]; ag += w * g_in[f];
    }
    int lane = t & 63, wv = t >> 6;
    for (int off = 1; off < 64; off <<= 1){ ab += __shfl_xor(ab, off); ag += __shfl_xor(ag, off); }
    if (lane == 0){ ra[wv] = ab; rb[wv] = ag; }
    __syncthreads();
    if (t == 0){ wb[o] = ra[0]+ra[1]+ra[2]+ra[3]; wg[o] = rb[0]+rb[1]+rb[2]+rb[3]; }
  } else if (blk < 4608){
    int idx = (blk-4352)*256 + t; slots[idx] = prev_slots[idx];
  } else {                                           // zero q padding rows 8..15
    int idx = (blk-4608)*256 + t;
    int b = idx >> 11, rem = idx & 2047, rr = rem >> 8, d = rem & 255;
    qb[b*4096 + (8+rr)*256 + d] = 0;
  }
}

// ---------------------------------------------------------------- row stats
// One wave per feature row: mean + rstd (population var, eps=1e-5).
__global__ __launch_bounds__(256) void stats_kernel(const float* feat, float* meanv, float* rstdv){
  int t = threadIdx.x, w = t >> 6, lane = t & 63;
  int row = blockIdx.x*4 + w;
  const float4* fp = (const float4*)(feat + (size_t)row * 768);
  float s = 0.f, q = 0.f;
  for (int i = 0; i < 3; ++i){
    float4 v = fp[lane + 64*i];
    s += v.x + v.y + v.z + v.w;
    q += v.x*v.x + v.y*v.y + v.z*v.z + v.w*v.w;
  }
  for (int off = 1; off < 64; off <<= 1){ s += __shfl_xor(s, off); q += __shfl_xor(q, off); }
  if (lane == 0){
    float m = s * (1.f/768.f);
    meanv[row] = m;
    rstdv[row] = rsqrtf(q * (1.f/768.f) - m*m + LN_EPS);
  }
}

// ---------------------------------------------------------------- k/v projection GEMM
// C[131072 x 512] = bf16(x) · Wg^T with LN folded into the epilogue:
//   out = rstd*(acc - mean*wg[col]) + wb[col].  Output bf16 (k|v interleaved per row).
// Block: 64 rows x 512 cols, 4 waves (each 64x128), BK=32, 16x16x32 MFMA.
__global__ __launch_bounds__(256, 2) void kv_gemm(
    const float* feat, const ushort* Wg, const float* wb, const float* wg,
    const float* meanv, const float* rstdv, ushort* kv)
{
  int blk = blockIdx.x; int r0 = blk * 64;
  int t = threadIdx.x, w = t >> 6, lane = t & 63, m16 = lane & 15, quad = lane >> 4;
  __shared__ __align__(16) uint As[64*20];    // 64 rows x 32 bf16, stride 40 bf16 (odd 16B units)
  __shared__ __align__(16) uint Bs[512*20];   // 512 cols x 32 bf16, stride 40 bf16
  __shared__ float mr_m[64], mr_r[64], wbl[512], wgl[512];
  if (t < 64){ mr_m[t] = meanv[r0 + t]; mr_r[t] = rstdv[r0 + t]; }
  wbl[t] = wb[t]; wbl[t+256] = wb[t+256];
  wgl[t] = wg[t]; wgl[t+256] = wg[t+256];

  f32x4 acc[4][8];
  #pragma unroll
  for (int i = 0; i < 4; ++i)
    #pragma unroll
    for (int j = 0; j < 8; ++j) acc[i][j] = (f32x4){0.f,0.f,0.f,0.f};

  for (int k0 = 0; k0 < 768; k0 += 32){
    __syncthreads();
    // stage A: 64x32 f32 -> bf16 LDS
    #pragma unroll
    for (int i = 0; i < 2; ++i){
      int c = t + 256*i;
      int row = c >> 3, f4i = c & 7;
      float4 v = *(const float4*)(feat + (size_t)(r0+row)*768 + k0 + f4i*4);
      uint2 pk; pk.x = pack2(v.x, v.y); pk.y = pack2(v.z, v.w);
      *(uint2*)&As[row*20 + f4i*2] = pk;
    }
    // stage B: 512x32 bf16 LDS
    #pragma unroll
    for (int i = 0; i < 8; ++i){
      int c = t + 256*i;
      int o = c >> 2, ko = c & 3;
      uint4 wv = *(const uint4*)(Wg + (size_t)o*768 + k0 + ko*8);
      *(uint4*)&Bs[o*20 + ko*4] = wv;
    }
    __syncthreads();
    bf16x8 af[4];
    #pragma unroll
    for (int i = 0; i < 4; ++i)
      af[i] = __builtin_bit_cast(bf16x8, *(const uint4*)&As[(16*i + m16)*20 + quad*4]);
    #pragma unroll
    for (int j = 0; j < 8; ++j){
      bf16x8 bfv = __builtin_bit_cast(bf16x8, *(const uint4*)&Bs[(w*128 + 16*j + m16)*20 + quad*4]);
      #pragma unroll
      for (int i = 0; i < 4; ++i) acc[i][j] = mfma16(af[i], bfv, acc[i][j]);
    }
  }
  // epilogue: C/D layout row=(quad*4+r), col=lane&15
  #pragma unroll
  for (int i = 0; i < 4; ++i){
    #pragma unroll
    for (int j = 0; j < 8; ++j){
      int col = w*128 + 16*j + m16;
      float wgc = wgl[col], wbc = wbl[col];
      f32x4 c = acc[i][j];
      #pragma unroll
      for (int r = 0; r < 4; ++r){
        int row = 16*i + quad*4 + r;
        float val = mr_r[row] * (c[r] - mr_m[row]*wgc) + wbc;
        kv[(size_t)(r0+row)*512 + col] = f2bf(val);
      }
    }
  }
}

// ---------------------------------------------------------------- q projection
// One block per (b,slot): LN(slots; g_s,b_s) then q = ln · Wq^T, scaled by 1/16, bf16 out.
__global__ __launch_bounds__(256) void q_kernel(
    const float* slots, const ushort* Wqb, const float* g_s, const float* b_s, ushort* qb)
{
  int blk = blockIdx.x; int b = blk >> 3, kk = blk & 7;
  int t = threadIdx.x, lane = t & 63, w = t >> 6;
  __shared__ __align__(16) float ln_l[256];
  __shared__ float ra[4], rb[4];
  float x = slots[blk*256 + t];
  float s = x, q = x*x;
  for (int off = 1; off < 64; off <<= 1){ s += __shfl_xor(s, off); q += __shfl_xor(q, off); }
  if (lane == 0){ ra[w] = s; rb[w] = q; }
  __syncthreads();
  float S = ra[0]+ra[1]+ra[2]+ra[3], Q = rb[0]+rb[1]+rb[2]+rb[3];
  float mean = S * (1.f/256.f);
  float rstd = rsqrtf(Q * (1.f/256.f) - mean*mean + LN_EPS);
  ln_l[t] = (x - mean)*rstd*g_s[t] + b_s[t];
  __syncthreads();
  float acc = 0.f;
  const uint4* wq = (const uint4*)(Wqb + (size_t)t*256);
  for (int c = 0; c < 32; ++c){
    float wf[8]; unpk8(wq[c], wf);
    const float* lp = &ln_l[c*8];
    #pragma unroll
    for (int j = 0; j < 8; ++j) acc += wf[j]*lp[j];
  }
  qb[(size_t)(b*16 + kk)*256 + t] = f2bf(acc * QSCALE);
}

// ---------------------------------------------------------------- attention
// Block = (chunk of 256 positions, batch). Phase A: logits by MFMA (q in A-frags,
// k streamed from global), softmax over slot axis in C/D regs (shfl_xor 16).
// Phase B (mode 0): updates += P·v by VALU outer product, partials to ws.
// mode 1: write softmax attn to d_out and per-slot sums only.
__global__ __launch_bounds__(256) void attn_kernel(
    const ushort* kv, const ushort* qb,
    float* upd_part, float* sum_part, float* attn_out, int mode)
{
  int chunk = blockIdx.x, b = blockIdx.y;
  int t = threadIdx.x, w = t >> 6, lane = t & 63, m16 = lane & 15, quad = lane >> 4;
  int n0 = chunk * 256;
  __shared__ __align__(16) float PT[256*9];     // P transposed [pos][slot], stride 9
  __shared__ float wsum[4][8];
  __shared__ __align__(16) float red[8*2048];   // phase-B cross-pg reduction

  bf16x8 af[8];
  {
    const uint4* qp = (const uint4*)(qb + ((size_t)(b*16 + m16))*256);
    #pragma unroll
    for (int ks = 0; ks < 8; ++ks) af[ks] = __builtin_bit_cast(bf16x8, qp[ks*4 + quad]);
  }
  const ushort* kvb = kv + ((size_t)(b*4096 + n0))*512;
  f32x4 acc[4];
  #pragma unroll
  for (int nf = 0; nf < 4; ++nf) acc[nf] = (f32x4){0.f,0.f,0.f,0.f};
  #pragma unroll
  for (int ks = 0; ks < 8; ++ks){
    #pragma unroll
    for (int nf = 0; nf < 4; ++nf){
      const uint4* bp = (const uint4*)(kvb + ((size_t)(w*64 + nf*16 + m16))*512);
      bf16x8 bv = __builtin_bit_cast(bf16x8, bp[ks*4 + quad]);
      acc[nf] = mfma16(af[ks], bv, acc[nf]);
    }
  }
  float sacc[4] = {0.f,0.f,0.f,0.f};
  #pragma unroll
  for (int nf = 0; nf < 4; ++nf){
    float l0 = acc[nf][0], l1 = acc[nf][1], l2 = acc[nf][2], l3 = acc[nf][3];
    float mx = fmaxf(fmaxf(l0,l1), fmaxf(l2,l3));
    mx = fmaxf(mx, __shfl_xor(mx, 16));
    float e0 = __expf(l0-mx), e1 = __expf(l1-mx), e2 = __expf(l2-mx), e3 = __expf(l3-mx);
    float s = e0+e1+e2+e3;
    s += __shfl_xor(s, 16);
    float inv = 1.f / s;
    e0 *= inv; e1 *= inv; e2 *= inv; e3 *= inv;
    if (quad < 2){                       // quads 0,1 hold real slots 0..7
      sacc[0]+=e0; sacc[1]+=e1; sacc[2]+=e2; sacc[3]+=e3;
      int pos = w*64 + nf*16 + m16;
      if (mode == 0){
        PT[pos*9 + quad*4 + 0] = e0;
        PT[pos*9 + quad*4 + 1] = e1;
        PT[pos*9 + quad*4 + 2] = e2;
        PT[pos*9 + quad*4 + 3] = e3;
      } else {
        int slot = quad*4;
        attn_out[((size_t)(b*8 + slot+0))*4096 + n0 + pos] = e0;
        attn_out[((size_t)(b*8 + slot+1))*4096 + n0 + pos] = e1;
        attn_out[((size_t)(b*8 + slot+2))*4096 + n0 + pos] = e2;
        attn_out[((size_t)(b*8 + slot+3))*4096 + n0 + pos] = e3;
      }
    }
  }
  for (int off = 1; off < 16; off <<= 1){
    sacc[0] += __shfl_xor(sacc[0], off);
    sacc[1] += __shfl_xor(sacc[1], off);
    sacc[2] += __shfl_xor(sacc[2], off);
    sacc[3] += __shfl_xor(sacc[3], off);
  }
  if (m16 == 0 && quad < 2){
    wsum[w][quad*4+0] = sacc[0]; wsum[w][quad*4+1] = sacc[1];
    wsum[w][quad*4+2] = sacc[2]; wsum[w][quad*4+3] = sacc[3];
  }
  __syncthreads();
  if (t < 8){
    float s = wsum[0][t] + wsum[1][t] + wsum[2][t] + wsum[3][t];
    sum_part[(b*16 + chunk)*8 + t] = s;
  }
  if (mode) return;
  // ---- phase B: thread = (pgroup of 32 positions, dgroup of 8 dims), 64 accs
  int dg = t & 31, pg = t >> 5;
  float ua[8][8];
  #pragma unroll
  for (int k = 0; k < 8; ++k)
    #pragma unroll
    for (int j = 0; j < 8; ++j) ua[k][j] = 0.f;
  const ushort* vb = kv + ((size_t)(b*4096 + n0))*512 + 256;
  for (int i = 0; i < 32; ++i){
    int p = pg*32 + i;
    uint4 vv = *(const uint4*)(vb + (size_t)p*512 + dg*8);
    float vf[8]; unpk8(vv, vf);
    #pragma unroll
    for (int k = 0; k < 8; ++k){
      float a = PT[p*9 + k];
      #pragma unroll
      for (int j = 0; j < 8; ++j) ua[k][j] += a * vf[j];
    }
  }
  #pragma unroll
  for (int k = 0; k < 8; ++k){
    *(float4*)&red[pg*2048 + k*256 + dg*8]     = make_float4(ua[k][0],ua[k][1],ua[k][2],ua[k][3]);
    *(float4*)&red[pg*2048 + k*256 + dg*8 + 4] = make_float4(ua[k][4],ua[k][5],ua[k][6],ua[k][7]);
  }
  __syncthreads();
  #pragma unroll
  for (int j = 0; j < 8; ++j){
    float s = 0.f;
    #pragma unroll
    for (int pgi = 0; pgi < 8; ++pgi) s += red[pgi*2048 + j*256 + t];
    upd_part[((size_t)((b*16 + chunk)*8 + j))*256 + t] = s;
  }
}

// ---------------------------------------------------------------- GRU + MLP
// Block = (b,slot). Reduces update partials, normalizes by (sum+eps), torch GRUCell
// (r,z,n order), then LN + 2-layer MLP with residual. Updates slots in place.
__global__ __launch_bounds__(256) void gru_kernel(
    const float* upd_part, const float* sum_part, float* slots,
    const ushort* Wihb, const ushort* Whhb, const ushort* W1b, const ushort* W2b,
    const float* b_ih, const float* b_hh, const float* g_m, const float* b_m,
    const float* b1, const float* b2)
{
  int blk = blockIdx.x; int b = blk >> 3, k = blk & 7;
  int t = threadIdx.x, lane = t & 63, w = t >> 6;
  __shared__ __align__(16) float u_l[256], s_l[256], lnh[256], m1_l[256];
  __shared__ float ra[4], rb[4];
  float stot = EPS_SUM;
  for (int c = 0; c < 16; ++c) stot += sum_part[(b*16 + c)*8 + k];
  float us = 0.f;
  for (int c = 0; c < 16; ++c) us += upd_part[((size_t)((b*16 + c)*8 + k))*256 + t];
  u_l[t] = us / stot;
  s_l[t] = slots[blk*256 + t];
  __syncthreads();
  float gi[3], gh[3];
  for (int gg = 0; gg < 3; ++gg){
    int g = gg*256 + t;
    float ai = b_ih[g], ah = b_hh[g];
    const uint4* wi = (const uint4*)(Wihb + (size_t)g*256);
    const uint4* wh = (const uint4*)(Whhb + (size_t)g*256);
    for (int c = 0; c < 32; ++c){
      float wf[8], hf[8];
      unpk8(wi[c], wf); unpk8(wh[c], hf);
      const float* up = &u_l[c*8];
      const float* sp = &s_l[c*8];
      #pragma unroll
      for (int j = 0; j < 8; ++j){ ai += wf[j]*up[j]; ah += hf[j]*sp[j]; }
    }
    gi[gg] = ai; gh[gg] = ah;
  }
  float r = 1.f/(1.f + __expf(-(gi[0] + gh[0])));
  float z = 1.f/(1.f + __expf(-(gi[1] + gh[1])));
  float n = tanhf(gi[2] + r*gh[2]);
  float h = (1.f - z)*n + z*s_l[t];
  // LN(h)
  float s = h, q = h*h;
  for (int off = 1; off < 64; off <<= 1){ s += __shfl_xor(s, off); q += __shfl_xor(q, off); }
  if (lane == 0){ ra[w] = s; rb[w] = q; }
  __syncthreads();
  float S = ra[0]+ra[1]+ra[2]+ra[3], Q = rb[0]+rb[1]+rb[2]+rb[3];
  float mean = S * (1.f/256.f);
  float rstd = rsqrtf(Q * (1.f/256.f) - mean*mean + LN_EPS);
  lnh[t] = (h - mean)*rstd*g_m[t] + b_m[t];
  __syncthreads();
  float a1 = b1[t];
  {
    const uint4* w1 = (const uint4*)(W1b + (size_t)t*256);
    for (int c = 0; c < 32; ++c){
      float wf[8]; unpk8(w1[c], wf);
      const float* lp = &lnh[c*8];
      #pragma unroll
      for (int j = 0; j < 8; ++j) a1 += wf[j]*lp[j];
    }
  }
  m1_l[t] = fmaxf(a1, 0.f);
  __syncthreads();
  float a2 = b2[t];
  {
    const uint4* w2 = (const uint4*)(W2b + (size_t)t*256);
    for (int c = 0; c < 32; ++c){
      float wf[8]; unpk8(w2[c], wf);
      const float* mp = &m1_l[c*8];
      #pragma unroll
      for (int j = 0; j < 8; ++j) a2 += wf[j]*mp[j];
    }
  }
  slots[blk*256 + t] = h + a2;
}

// ---------------------------------------------------------------- final blend
__global__ __launch_bounds__(256) void blend_kernel(
    const float* slots, const float* prev, const float* sum_part, float* out)
{
  int blk = blockIdx.x; int b = blk >> 3, k = blk & 7;
  int t = threadIdx.x;
  float s = 0.f;
  for (int c = 0; c < 16; ++c) s += sum_part[(b*16 + c)*8 + k];
  float mean = s * (1.f/4096.f);
  float mask = 1.f/(1.f + __expf(-mean));
  int idx = blk*256 + t;
  out[idx] = slots[idx]*mask + prev[idx]*(1.f - mask);
}

// ---------------------------------------------------------------- launch
extern "C" void kernel_launch(void* const* d_in, const int* in_sizes, int n_in,
                              void* d_out, int out_size, void* d_ws, size_t ws_size,
                              hipStream_t stream)
{
  (void)in_sizes; (void)n_in; (void)out_size; (void)ws_size;
  const float* feat = (const float*)d_in[0];
  const float* prev = (const float*)d_in[1];
  const float* g_in = (const float*)d_in[2];
  const float* b_in = (const float*)d_in[3];
  const float* g_s  = (const float*)d_in[4];
  const float* b_s  = (const float*)d_in[5];
  const float* g_m  = (const float*)d_in[6];
  const float* b_m  = (const float*)d_in[7];
  const float* Wq   = (const float*)d_in[8];
  const float* Wk   = (const float*)d_in[9];
  const float* Wv   = (const float*)d_in[10];
  const float* W_ih = (const float*)d_in[11];
  const float* W_hh = (const float*)d_in[12];
  const float* b_ih = (const float*)d_in[13];
  const float* b_hh = (const float*)d_in[14];
  const float* W1   = (const float*)d_in[15];
  const float* b1   = (const float*)d_in[16];
  const float* W2   = (const float*)d_in[17];
  const float* b2   = (const float*)d_in[18];
  float* out = (float*)d_out;

  char* ws = (char*)d_ws;
  size_t off = 0;
  auto alloc = [&](size_t bytes)->void*{
    void* p = ws + off;
    off = (off + bytes + 255) & ~(size_t)255;
    return p;
  };
  ushort* kv    = (ushort*)alloc((size_t)ROWS*512*2);   // 134 MB
  ushort* Wg    = (ushort*)alloc((size_t)512*768*2);
  float*  wbv   = (float*) alloc(512*4);
  float*  wgv   = (float*) alloc(512*4);
  float*  meanv = (float*) alloc((size_t)ROWS*4);
  float*  rstdv = (float*) alloc((size_t)ROWS*4);
  ushort* Wihb  = (ushort*)alloc((size_t)768*256*2);
  ushort* Whhb  = (ushort*)alloc((size_t)768*256*2);
  ushort* W1b   = (ushort*)alloc((size_t)256*256*2);
  ushort* W2b   = (ushort*)alloc((size_t)256*256*2);
  ushort* Wqb   = (ushort*)alloc((size_t)256*256*2);
  float*  slots = (float*) alloc((size_t)65536*4);
  ushort* qb    = (ushort*)alloc((size_t)32*16*256*2);
  float*  updp  = (float*) alloc((size_t)32*16*8*256*4);
  float*  sump  = (float*) alloc((size_t)32*16*8*4);

  prep_kernel<<<4864, 256, 0, stream>>>(Wk, Wv, g_in, b_in, W_ih, W_hh, W1, W2, Wq, prev,
      Wg, Wihb, Whhb, W1b, W2b, Wqb, wbv, wgv, slots, qb);
  stats_kernel<<<ROWS/4, 256, 0, stream>>>(feat, meanv, rstdv);
  kv_gemm<<<ROWS/64, 256, 0, stream>>>(feat, Wg, wbv, wgv, meanv, rstdv, kv);

  float* attn_out = out + 65536;
  for (int it = 0; it < 3; ++it){
    q_kernel<<<256, 256, 0, stream>>>(slots, Wqb, g_s, b_s, qb);
    attn_kernel<<<dim3(16, 32), 256, 0, stream>>>(kv, qb, updp, sump, attn_out, 0);
    gru_kernel<<<256, 256, 0, stream>>>(updp, sump, slots, Wihb, Whhb, W1b, W2b,
        b_ih, b_hh, g_m, b_m, b1, b2);
  }
  q_kernel<<<256, 256, 0, stream>>>(slots, Wqb, g_s, b_s, qb);
  attn_kernel<<<dim3(16, 32), 256, 0, stream>>>(kv, qb, updp, sump, attn_out, 1);
  blend_kernel<<<256, 256, 0, stream>>>(slots, prev, sump, out);
}

// Round 2
// 972.850 us; speedup vs baseline: 1.0431x; 1.0431x over previous
//
#include <hip/hip_runtime.h>

typedef unsigned int uint;
typedef unsigned short ushort;
typedef __bf16 bf16x8 __attribute__((ext_vector_type(8)));
typedef float f32x4 __attribute__((ext_vector_type(4)));

#define B_SZ 32
#define N_SEQ 4096
#define ROWS (B_SZ * N_SEQ)   // 131072
#define LN_EPS 1e-5f
#define EPS_SUM 1e-8f
#define QSCALE 0.0625f        // 256^-0.5

__device__ inline float u2f(uint x){ union{uint u; float f;} c; c.u = x; return c.f; }
__device__ inline ushort f2bf(float f){
  union{float f; uint u;} c; c.f = f; uint u = c.u;
  return (ushort)((u + 0x7fffu + ((u >> 16) & 1u)) >> 16);   // RNE
}
__device__ inline uint pack2(float a, float b){ return (uint)f2bf(a) | ((uint)f2bf(b) << 16); }
__device__ inline void unpk8(uint4 u, float* o){
  o[0]=u2f(u.x<<16); o[1]=u2f(u.x&0xffff0000u);
  o[2]=u2f(u.y<<16); o[3]=u2f(u.y&0xffff0000u);
  o[4]=u2f(u.z<<16); o[5]=u2f(u.z&0xffff0000u);
  o[6]=u2f(u.w<<16); o[7]=u2f(u.w&0xffff0000u);
}
__device__ inline f32x4 mfma16(bf16x8 a, bf16x8 b, f32x4 c){
  return __builtin_amdgcn_mfma_f32_16x16x32_bf16(a, b, c, 0, 0, 0);
}
// async global->LDS, 16B per lane; lptr must be wave-uniform (lane i lands at lptr + i*16)
typedef const __attribute__((address_space(1))) void ga_void;
typedef __attribute__((address_space(3))) void ls_void;
__device__ inline void gll16(const void* g, void* l){
  __builtin_amdgcn_global_load_lds((ga_void*)g, (ls_void*)l, 16, 0, 0);
}

// ---------------------------------------------------------------- prep
// Casts all weights to bf16, computes wb/wg LN-fold vectors, copies
// prev_slots into working slots, zeroes q rows 8..15 (slot padding).
__global__ __launch_bounds__(256) void prep_kernel(
    const float* Wk, const float* Wv, const float* g_in, const float* b_in,
    const float* W_ih, const float* W_hh, const float* W1, const float* W2, const float* Wq,
    const float* prev_slots,
    ushort* Wg, ushort* Wihb, ushort* Whhb, ushort* W1b, ushort* W2b, ushort* Wqb,
    float* wb, float* wg, float* slots, ushort* qb)
{
  __shared__ float ra[4], rb[4];
  int blk = blockIdx.x, t = threadIdx.x;
  if (blk < 1536){                                   // Wg = [Wk;Wv] * g_in  (512x768)
    int idx = blk*256 + t;
    int o = idx / 768, f = idx - o*768;
    float w = (o < 256) ? Wk[o*768 + f] : Wv[(o-256)*768 + f];
    Wg[idx] = f2bf(w * g_in[f]);
  } else if (blk < 2304){
    int idx = (blk-1536)*256 + t; Wihb[idx] = f2bf(W_ih[idx]);
  } else if (blk < 3072){
    int idx = (blk-2304)*256 + t; Whhb[idx] = f2bf(W_hh[idx]);
  } else if (blk < 3328){
    int idx = (blk-3072)*256 + t; W1b[idx] = f2bf(W1[idx]);
  } else if (blk < 3584){
    int idx = (blk-3328)*256 + t; W2b[idx] = f2bf(W2[idx]);
  } else if (blk < 3840){
    int idx = (blk-3584)*256 + t; Wqb[idx] = f2bf(Wq[idx]);
  } else if (blk < 4352){                            // wb[o]=Σ W·b_in ; wg[o]=Σ W·g_in
    int o = blk - 3840;
    float ab = 0.f, ag = 0.f;
    for (int i = 0; i < 3; ++i){
      int f = t + 256*i;
      float w = (o < 256) ? Wk[o*768 + f] : Wv[(o-256)*768 + f];
      ab += w * b_in[f]; ag += w * g_in[f];
    }
    int lane = t & 63, wv = t >> 6;
    for (int off = 1; off < 64; off <<= 1){ ab += __shfl_xor(ab, off); ag += __shfl_xor(ag, off); }
    if (lane == 0){ ra[wv] = ab; rb[wv] = ag; }
    __syncthreads();
    if (t == 0){ wb[o] = ra[0]+ra[1]+ra[2]+ra[3]; wg[o] = rb[0]+rb[1]+rb[2]+rb[3]; }
  } else if (blk < 4608){
    int idx = (blk-4352)*256 + t; slots[idx] = prev_slots[idx];
  } else {                                           // zero q padding rows 8..15
    int idx = (blk-4608)*256 + t;
    int b = idx >> 11, rem = idx & 2047, rr = rem >> 8, d = rem & 255;
    qb[b*4096 + (8+rr)*256 + d] = 0;
  }
}

// ---------------------------------------------------------------- cvt + stats
// One wave per feature row: write bf16 copy of the row, plus mean + rstd.
__global__ __launch_bounds__(256) void cvt_stats_kernel(
    const float* feat, ushort* featb, float* meanv, float* rstdv)
{
  int t = threadIdx.x, w = t >> 6, lane = t & 63;
  int row = blockIdx.x*4 + w;
  const float4* fp = (const float4*)(feat + (size_t)row * 768);
  uint2* ob = (uint2*)(featb + (size_t)row * 768);
  float s = 0.f, q = 0.f;
  #pragma unroll
  for (int i = 0; i < 3; ++i){
    float4 v = fp[lane + 64*i];
    s += v.x + v.y + v.z + v.w;
    q += v.x*v.x + v.y*v.y + v.z*v.z + v.w*v.w;
    uint2 pk; pk.x = pack2(v.x, v.y); pk.y = pack2(v.z, v.w);
    ob[lane + 64*i] = pk;
  }
  for (int off = 1; off < 64; off <<= 1){ s += __shfl_xor(s, off); q += __shfl_xor(q, off); }
  if (lane == 0){
    float m = s * (1.f/768.f);
    meanv[row] = m;
    rstdv[row] = rsqrtf(q * (1.f/768.f) - m*m + LN_EPS);
  }
}

// ---------------------------------------------------------------- k/v projection GEMM
// m97-style: 128x128 tile, BK=64, 4 waves (each 64x64 via 4x4 accs of 16x16x32).
// A = bf16 features (global_load_lds x4), B = Wg bf16 (global_load_lds x4).
// LDS K-chunk placement XOR-swizzled by (row&7) so ds_read_b128 frag reads are
// conflict-free (8 bank-groups, 2-way alias).
// Epilogue folds LN: out = rstd*(acc - mean*wg[col]) + wb[col], bf16 store.
__global__ __launch_bounds__(256) void kv_gemm(
    const ushort* featb, const ushort* Wg, const float* wb, const float* wg,
    const float* meanv, const float* rstdv, ushort* kv)
{
  int r0 = blockIdx.x * 128, c0 = blockIdx.y * 128;
  int t = threadIdx.x, w = t >> 6, lane = t & 63, m16 = lane & 15, quad = lane >> 4;
  __shared__ __align__(16) ushort As[128*64];
  __shared__ __align__(16) ushort Bs[128*64];
  __shared__ float mr_m[128], mr_r[128], wbl[128], wgl[128];
  if (t < 128){
    mr_m[t] = meanv[r0 + t]; mr_r[t] = rstdv[r0 + t];
    wbl[t] = wb[c0 + t];     wgl[t] = wg[c0 + t];
  }
  int wr = (w >> 1) * 64, wc = (w & 1) * 64;
  int srow = t >> 3, skc = t & 7;          // staging: thread -> (row, lds k-chunk)

  f32x4 acc[4][4];
  #pragma unroll
  for (int i = 0; i < 4; ++i)
    #pragma unroll
    for (int j = 0; j < 4; ++j) acc[i][j] = (f32x4){0.f,0.f,0.f,0.f};

  for (int k0 = 0; k0 < 768; k0 += 64){
    if (k0) __syncthreads();
    #pragma unroll
    for (int i = 0; i < 4; ++i){
      int row = srow + i*32;
      int kcg = skc ^ (row & 7);
      gll16(featb + (size_t)(r0+row)*768 + k0 + kcg*8, As + (i*256 + w*64)*8);
    }
    #pragma unroll
    for (int i = 0; i < 4; ++i){
      int col = srow + i*32;
      int kcg = skc ^ (col & 7);
      gll16(Wg + (size_t)(c0+col)*768 + k0 + kcg*8, Bs + (i*256 + w*64)*8);
    }
    __syncthreads();
    bf16x8 af[4][2], bfr[4][2];
    #pragma unroll
    for (int i = 0; i < 4; ++i){
      int row = wr + 16*i + m16;
      #pragma unroll
      for (int h = 0; h < 2; ++h){
        int kc = (quad + h*4) ^ (row & 7);
        af[i][h] = __builtin_bit_cast(bf16x8, *(const uint4*)&As[(row*8 + kc)*8]);
      }
    }
    #pragma unroll
    for (int j = 0; j < 4; ++j){
      int col = wc + 16*j + m16;
      #pragma unroll
      for (int h = 0; h < 2; ++h){
        int kc = (quad + h*4) ^ (col & 7);
        bfr[j][h] = __builtin_bit_cast(bf16x8, *(const uint4*)&Bs[(col*8 + kc)*8]);
      }
    }
    #pragma unroll
    for (int j = 0; j < 4; ++j)
      #pragma unroll
      for (int i = 0; i < 4; ++i){
        acc[i][j] = mfma16(af[i][0], bfr[j][0], acc[i][j]);
        acc[i][j] = mfma16(af[i][1], bfr[j][1], acc[i][j]);
      }
  }
  // epilogue: C/D layout row=(quad*4+r), col=m16 within each 16x16 tile
  #pragma unroll
  for (int i = 0; i < 4; ++i){
    #pragma unroll
    for (int j = 0; j < 4; ++j){
      int col = wc + 16*j + m16;
      float wgc = wgl[col], wbc = wbl[col];
      f32x4 c = acc[i][j];
      #pragma unroll
      for (int r = 0; r < 4; ++r){
        int row = wr + 16*i + quad*4 + r;
        float val = mr_r[row] * (c[r] - mr_m[row]*wgc) + wbc;
        kv[(size_t)(r0+row)*512 + c0 + col] = f2bf(val);
      }
    }
  }
}

// ---------------------------------------------------------------- q projection
// One block per (b,slot): LN(slots; g_s,b_s) then q = ln · Wq^T, scaled by 1/16, bf16 out.
__global__ __launch_bounds__(256) void q_kernel(
    const float* slots, const ushort* Wqb, const float* g_s, const float* b_s, ushort* qb)
{
  int blk = blockIdx.x; int b = blk >> 3, kk = blk & 7;
  int t = threadIdx.x, lane = t & 63, w = t >> 6;
  __shared__ __align__(16) float ln_l[256];
  __shared__ float ra[4], rb[4];
  float x = slots[blk*256 + t];
  float s = x, q = x*x;
  for (int off = 1; off < 64; off <<= 1){ s += __shfl_xor(s, off); q += __shfl_xor(q, off); }
  if (lane == 0){ ra[w] = s; rb[w] = q; }
  __syncthreads();
  float S = ra[0]+ra[1]+ra[2]+ra[3], Q = rb[0]+rb[1]+rb[2]+rb[3];
  float mean = S * (1.f/256.f);
  float rstd = rsqrtf(Q * (1.f/256.f) - mean*mean + LN_EPS);
  ln_l[t] = (x - mean)*rstd*g_s[t] + b_s[t];
  __syncthreads();
  float acc = 0.f;
  const uint4* wq = (const uint4*)(Wqb + (size_t)t*256);
  for (int c = 0; c < 32; ++c){
    float wf[8]; unpk8(wq[c], wf);
    const float* lp = &ln_l[c*8];
    #pragma unroll
    for (int j = 0; j < 8; ++j) acc += wf[j]*lp[j];
  }
  qb[(size_t)(b*16 + kk)*256 + t] = f2bf(acc * QSCALE);
}

// ---------------------------------------------------------------- attention
// Block = (chunk of 256 positions, batch). Phase A: logits by MFMA (q in A-frags,
// k streamed from global), softmax over slot axis in C/D regs (shfl_xor 16).
// Phase B (mode 0): updates += P·v by VALU outer product, partials to ws.
// mode 1: write softmax attn to d_out and per-slot sums only.
__global__ __launch_bounds__(256) void attn_kernel(
    const ushort* kv, const ushort* qb,
    float* upd_part, float* sum_part, float* attn_out, int mode)
{
  int chunk = blockIdx.x, b = blockIdx.y;
  int t = threadIdx.x, w = t >> 6, lane = t & 63, m16 = lane & 15, quad = lane >> 4;
  int n0 = chunk * 256;
  __shared__ __align__(16) float PT[256*9];     // P transposed [pos][slot], stride 9
  __shared__ float wsum[4][8];
  __shared__ __align__(16) float red[8*2048];   // phase-B cross-pg reduction

  bf16x8 af[8];
  {
    const uint4* qp = (const uint4*)(qb + ((size_t)(b*16 + m16))*256);
    #pragma unroll
    for (int ks = 0; ks < 8; ++ks) af[ks] = __builtin_bit_cast(bf16x8, qp[ks*4 + quad]);
  }
  const ushort* kvb = kv + ((size_t)(b*4096 + n0))*512;
  f32x4 acc[4];
  #pragma unroll
  for (int nf = 0; nf < 4; ++nf) acc[nf] = (f32x4){0.f,0.f,0.f,0.f};
  #pragma unroll
  for (int ks = 0; ks < 8; ++ks){
    #pragma unroll
    for (int nf = 0; nf < 4; ++nf){
      const uint4* bp = (const uint4*)(kvb + ((size_t)(w*64 + nf*16 + m16))*512);
      bf16x8 bv = __builtin_bit_cast(bf16x8, bp[ks*4 + quad]);
      acc[nf] = mfma16(af[ks], bv, acc[nf]);
    }
  }
  float sacc[4] = {0.f,0.f,0.f,0.f};
  #pragma unroll
  for (int nf = 0; nf < 4; ++nf){
    float l0 = acc[nf][0], l1 = acc[nf][1], l2 = acc[nf][2], l3 = acc[nf][3];
    float mx = fmaxf(fmaxf(l0,l1), fmaxf(l2,l3));
    mx = fmaxf(mx, __shfl_xor(mx, 16));
    float e0 = __expf(l0-mx), e1 = __expf(l1-mx), e2 = __expf(l2-mx), e3 = __expf(l3-mx);
    float s = e0+e1+e2+e3;
    s += __shfl_xor(s, 16);
    float inv = 1.f / s;
    e0 *= inv; e1 *= inv; e2 *= inv; e3 *= inv;
    if (quad < 2){                       // quads 0,1 hold real slots 0..7
      sacc[0]+=e0; sacc[1]+=e1; sacc[2]+=e2; sacc[3]+=e3;
      int pos = w*64 + nf*16 + m16;
      if (mode == 0){
        PT[pos*9 + quad*4 + 0] = e0;
        PT[pos*9 + quad*4 + 1] = e1;
        PT[pos*9 + quad*4 + 2] = e2;
        PT[pos*9 + quad*4 + 3] = e3;
      } else {
        int slot = quad*4;
        attn_out[((size_t)(b*8 + slot+0))*4096 + n0 + pos] = e0;
        attn_out[((size_t)(b*8 + slot+1))*4096 + n0 + pos] = e1;
        attn_out[((size_t)(b*8 + slot+2))*4096 + n0 + pos] = e2;
        attn_out[((size_t)(b*8 + slot+3))*4096 + n0 + pos] = e3;
      }
    }
  }
  for (int off = 1; off < 16; off <<= 1){
    sacc[0] += __shfl_xor(sacc[0], off);
    sacc[1] += __shfl_xor(sacc[1], off);
    sacc[2] += __shfl_xor(sacc[2], off);
    sacc[3] += __shfl_xor(sacc[3], off);
  }
  if (m16 == 0 && quad < 2){
    wsum[w][quad*4+0] = sacc[0]; wsum[w][quad*4+1] = sacc[1];
    wsum[w][quad*4+2] = sacc[2]; wsum[w][quad*4+3] = sacc[3];
  }
  __syncthreads();
  if (t < 8){
    float s = wsum[0][t] + wsum[1][t] + wsum[2][t] + wsum[3][t];
    sum_part[(b*16 + chunk)*8 + t] = s;
  }
  if (mode) return;
  // ---- phase B: thread = (pgroup of 32 positions, dgroup of 8 dims), 64 accs
  int dg = t & 31, pg = t >> 5;
  float ua[8][8];
  #pragma unroll
  for (int k = 0; k < 8; ++k)
    #pragma unroll
    for (int j = 0; j < 8; ++j) ua[k][j] = 0.f;
  const ushort* vb = kv + ((size_t)(b*4096 + n0))*512 + 256;
  for (int i = 0; i < 32; ++i){
    int p = pg*32 + i;
    uint4 vv = *(const uint4*)(vb + (size_t)p*512 + dg*8);
    float vf[8]; unpk8(vv, vf);
    #pragma unroll
    for (int k = 0; k < 8; ++k){
      float a = PT[p*9 + k];
      #pragma unroll
      for (int j = 0; j < 8; ++j) ua[k][j] += a * vf[j];
    }
  }
  #pragma unroll
  for (int k = 0; k < 8; ++k){
    *(float4*)&red[pg*2048 + k*256 + dg*8]     = make_float4(ua[k][0],ua[k][1],ua[k][2],ua[k][3]);
    *(float4*)&red[pg*2048 + k*256 + dg*8 + 4] = make_float4(ua[k][4],ua[k][5],ua[k][6],ua[k][7]);
  }
  __syncthreads();
  #pragma unroll
  for (int j = 0; j < 8; ++j){
    float s = 0.f;
    #pragma unroll
    for (int pgi = 0; pgi < 8; ++pgi) s += red[pgi*2048 + j*256 + t];
    upd_part[((size_t)((b*16 + chunk)*8 + j))*256 + t] = s;
  }
}

// ---------------------------------------------------------------- GRU + MLP
// Block = (b,slot). Reduces update partials, normalizes by (sum+eps), torch GRUCell
// (r,z,n order), then LN + 2-layer MLP with residual. Updates slots in place.
__global__ __launch_bounds__(256) void gru_kernel(
    const float* upd_part, const float* sum_part, float* slots,
    const ushort* Wihb, const ushort* Whhb, const ushort* W1b, const ushort* W2b,
    const float* b_ih, const float* b_hh, const float* g_m, const float* b_m,
    const float* b1, const float* b2)
{
  int blk = blockIdx.x; int b = blk >> 3, k = blk & 7;
  int t = threadIdx.x, lane = t & 63, w = t >> 6;
  __shared__ __align__(16) float u_l[256], s_l[256], lnh[256], m1_l[256];
  __shared__ float ra[4], rb[4];
  float stot = EPS_SUM;
  for (int c = 0; c < 16; ++c) stot += sum_part[(b*16 + c)*8 + k];
  float us = 0.f;
  for (int c = 0; c < 16; ++c) us += upd_part[((size_t)((b*16 + c)*8 + k))*256 + t];
  u_l[t] = us / stot;
  s_l[t] = slots[blk*256 + t];
  __syncthreads();
  float gi[3], gh[3];
  for (int gg = 0; gg < 3; ++gg){
    int g = gg*256 + t;
    float ai = b_ih[g], ah = b_hh[g];
    const uint4* wi = (const uint4*)(Wihb + (size_t)g*256);
    const uint4* wh = (const uint4*)(Whhb + (size_t)g*256);
    for (int c = 0; c < 32; ++c){
      float wf[8], hf[8];
      unpk8(wi[c], wf); unpk8(wh[c], hf);
      const float* up = &u_l[c*8];
      const float* sp = &s_l[c*8];
      #pragma unroll
      for (int j = 0; j < 8; ++j){ ai += wf[j]*up[j]; ah += hf[j]*sp[j]; }
    }
    gi[gg] = ai; gh[gg] = ah;
  }
  float r = 1.f/(1.f + __expf(-(gi[0] + gh[0])));
  float z = 1.f/(1.f + __expf(-(gi[1] + gh[1])));
  float n = tanhf(gi[2] + r*gh[2]);
  float h = (1.f - z)*n + z*s_l[t];
  // LN(h)
  float s = h, q = h*h;
  for (int off = 1; off < 64; off <<= 1){ s += __shfl_xor(s, off); q += __shfl_xor(q, off); }
  if (lane == 0){ ra[w] = s; rb[w] = q; }
  __syncthreads();
  float S = ra[0]+ra[1]+ra[2]+ra[3], Q = rb[0]+rb[1]+rb[2]+rb[3];
  float mean = S * (1.f/256.f);
  float rstd = rsqrtf(Q * (1.f/256.f) - mean*mean + LN_EPS);
  lnh[t] = (h - mean)*rstd*g_m[t] + b_m[t];
  __syncthreads();
  float a1 = b1[t];
  {
    const uint4* w1 = (const uint4*)(W1b + (size_t)t*256);
    for (int c = 0; c < 32; ++c){
      float wf[8]; unpk8(w1[c], wf);
      const float* lp = &lnh[c*8];
      #pragma unroll
      for (int j = 0; j < 8; ++j) a1 += wf[j]*lp[j];
    }
  }
  m1_l[t] = fmaxf(a1, 0.f);
  __syncthreads();
  float a2 = b2[t];
  {
    const uint4* w2 = (const uint4*)(W2b + (size_t)t*256);
    for (int c = 0; c < 32; ++c){
      float wf[8]; unpk8(w2[c], wf);
      const float* mp = &m1_l[c*8];
      #pragma unroll
      for (int j = 0; j < 8; ++j) a2 += wf[j]*mp[j];
    }
  }
  slots[blk*256 + t] = h + a2;
}

// ---------------------------------------------------------------- final blend
__global__ __launch_bounds__(256) void blend_kernel(
    const float* slots, const float* prev, const float* sum_part, float* out)
{
  int blk = blockIdx.x; int b = blk >> 3, k = blk & 7;
  int t = threadIdx.x;
  float s = 0.f;
  for (int c = 0; c < 16; ++c) s += sum_part[(b*16 + c)*8 + k];
  float mean = s * (1.f/4096.f);
  float mask = 1.f/(1.f + __expf(-mean));
  int idx = blk*256 + t;
  out[idx] = slots[idx]*mask + prev[idx]*(1.f - mask);
}

// ---------------------------------------------------------------- launch
extern "C" void kernel_launch(void* const* d_in, const int* in_sizes, int n_in,
                              void* d_out, int out_size, void* d_ws, size_t ws_size,
                              hipStream_t stream)
{
  (void)in_sizes; (void)n_in; (void)out_size; (void)ws_size;
  const float* feat = (const float*)d_in[0];
  const float* prev = (const float*)d_in[1];
  const float* g_in = (const float*)d_in[2];
  const float* b_in = (const float*)d_in[3];
  const float* g_s  = (const float*)d_in[4];
  const float* b_s  = (const float*)d_in[5];
  const float* g_m  = (const float*)d_in[6];
  const float* b_m  = (const float*)d_in[7];
  const float* Wq   = (const float*)d_in[8];
  const float* Wk   = (const float*)d_in[9];
  const float* Wv   = (const float*)d_in[10];
  const float* W_ih = (const float*)d_in[11];
  const float* W_hh = (const float*)d_in[12];
  const float* b_ih = (const float*)d_in[13];
  const float* b_hh = (const float*)d_in[14];
  const float* W1   = (const float*)d_in[15];
  const float* b1   = (const float*)d_in[16];
  const float* W2   = (const float*)d_in[17];
  const float* b2   = (const float*)d_in[18];
  float* out = (float*)d_out;

  char* ws = (char*)d_ws;
  size_t off = 0;
  auto alloc = [&](size_t bytes)->void*{
    void* p = ws + off;
    off = (off + bytes + 255) & ~(size_t)255;
    return p;
  };
  ushort* kv    = (ushort*)alloc((size_t)ROWS*512*2);   // 134 MB
  ushort* featb = (ushort*)alloc((size_t)ROWS*768*2);   // 201 MB
  ushort* Wg    = (ushort*)alloc((size_t)512*768*2);
  float*  wbv   = (float*) alloc(512*4);
  float*  wgv   = (float*) alloc(512*4);
  float*  meanv = (float*) alloc((size_t)ROWS*4);
  float*  rstdv = (float*) alloc((size_t)ROWS*4);
  ushort* Wihb  = (ushort*)alloc((size_t)768*256*2);
  ushort* Whhb  = (ushort*)alloc((size_t)768*256*2);
  ushort* W1b   = (ushort*)alloc((size_t)256*256*2);
  ushort* W2b   = (ushort*)alloc((size_t)256*256*2);
  ushort* Wqb   = (ushort*)alloc((size_t)256*256*2);
  float*  slots = (float*) alloc((size_t)65536*4);
  ushort* qb    = (ushort*)alloc((size_t)32*16*256*2);
  float*  updp  = (float*) alloc((size_t)32*16*8*256*4);
  float*  sump  = (float*) alloc((size_t)32*16*8*4);

  prep_kernel<<<4864, 256, 0, stream>>>(Wk, Wv, g_in, b_in, W_ih, W_hh, W1, W2, Wq, prev,
      Wg, Wihb, Whhb, W1b, W2b, Wqb, wbv, wgv, slots, qb);
  cvt_stats_kernel<<<ROWS/4, 256, 0, stream>>>(feat, featb, meanv, rstdv);
  kv_gemm<<<dim3(ROWS/128, 4), 256, 0, stream>>>(featb, Wg, wbv, wgv, meanv, rstdv, kv);

  float* attn_out = out + 65536;
  for (int it = 0; it < 3; ++it){
    q_kernel<<<256, 256, 0, stream>>>(slots, Wqb, g_s, b_s, qb);
    attn_kernel<<<dim3(16, 32), 256, 0, stream>>>(kv, qb, updp, sump, attn_out, 0);
    gru_kernel<<<256, 256, 0, stream>>>(updp, sump, slots, Wihb, Whhb, W1b, W2b,
        b_ih, b_hh, g_m, b_m, b1, b2);
  }
  q_kernel<<<256, 256, 0, stream>>>(slots, Wqb, g_s, b_s, qb);
  attn_kernel<<<dim3(16, 32), 256, 0, stream>>>(kv, qb, updp, sump, attn_out, 1);
  blend_kernel<<<256, 256, 0, stream>>>(slots, prev, sump, out);
}